// Round 12
// baseline (184.135 us; speedup 1.0000x reference)
//
#include <hip/hip_runtime.h>
#include <math.h>

// (B, F, NP, DIM, H, DH) = (4, 16, 196, 512, 8, 64)
#define B_   4
#define F_   16
#define NP_  196
#define DIM_ 512
#define H_   8
#define DH_  64
#define NTOT 3137            // 1 + F*NP
#define BH_  32              // B*H
#define MROWS 12548          // B*NTOT
#define QSZ_ ((size_t)BH_ * NTOT * DH_)   // elements per q/k/v buffer
#define PSTRIDE 232          // P LDS row stride (u16)
#define KSTRIDE 72           // K LDS row stride (u16)
#define VSTRIDE 232          // V^T LDS row stride (u16)
#define NGF 512              // BH_*16 cls partials

typedef unsigned short u16;
typedef __attribute__((ext_vector_type(8))) short    bf16x8;
typedef __attribute__((ext_vector_type(8))) unsigned short u16x8;
typedef __attribute__((ext_vector_type(4))) unsigned short u16x4;
typedef __attribute__((ext_vector_type(4))) float    f32x4;

__device__ __forceinline__ u16 f2bf(float f) {
    unsigned int u = __float_as_uint(f);
    unsigned int r = (u + 0x7FFFu + ((u >> 16) & 1u)) >> 16;
    return (u16)r;
}
__device__ __forceinline__ float bf2f(u16 u) {
    return __uint_as_float(((unsigned int)u) << 16);
}

// async global->LDS, 16B per lane. LDS dest must be wave-uniform base + lane*16.
__device__ __forceinline__ void gl2lds16(const u16* g, u16* l) {
    __builtin_amdgcn_global_load_lds(
        (const __attribute__((address_space(1))) unsigned int*)(g),
        (__attribute__((address_space(3))) unsigned int*)(l),
        16, 0, 0);
}

#define CFENCE  asm volatile("" ::: "memory")
#define WAITVM6 asm volatile("s_waitcnt vmcnt(6)" ::: "memory")
#define WAITVM0 asm volatile("s_waitcnt vmcnt(0)" ::: "memory")

// ---------------------------------------------------------------------------
// prep: fused convert_x + transpose(wqkv) + transpose(wout).
// ---------------------------------------------------------------------------
__global__ __launch_bounds__(256) void prep_kernel(
    const float* __restrict__ x, u16* __restrict__ xbf,
    const float* __restrict__ wqkv, u16* __restrict__ wqkvT,
    const float* __restrict__ wout, u16* __restrict__ woutT)
{
    __shared__ float t[32][33];
    const int blk = blockIdx.x, tid = threadIdx.x;

    if (blk < 6274) {
        int idx = blk * 256 + tid;
        float4 v = ((const float4*)x)[idx];
        u16x4 p = { f2bf(v.x), f2bf(v.y), f2bf(v.z), f2bf(v.w) };
        *(u16x4*)(&xbf[(size_t)idx * 4]) = p;
        return;
    }
    const float* src; u16* dst; int R, C, bx, by;
    if (blk < 7042) {
        int bb = blk - 6274;  src = wqkv; dst = wqkvT; R = 512; C = 1536;
        bx = bb % 48; by = bb / 48;
    } else {
        int bb = blk - 7042;  src = wout; dst = woutT; R = 512; C = 512;
        bx = bb % 16; by = bb / 16;
    }
    const int tx = tid & 31, ty = tid >> 5;
    const int c0 = bx * 32, r0 = by * 32;
    #pragma unroll
    for (int i = 0; i < 4; ++i) {
        int r = ty + i * 8;
        t[r][tx] = src[(size_t)(r0 + r) * C + c0 + tx];
    }
    __syncthreads();
    #pragma unroll
    for (int i = 0; i < 4; ++i) {
        int cc = ty + i * 8;
        dst[(size_t)(c0 + cc) * R + r0 + tx] = f2bf(t[tx][cc]);
    }
}

// ---------------------------------------------------------------------------
// 8-phase bf16 MFMA GEMM (round-12 T3+T4+T5 port):
//   C = A(MROWS x 512) * BT^T   (BT is N x 512 bf16, K-contiguous)
// 256x128 tile, 8 waves 4Mx2N (per-wave 64x64, acc[4][4] -- fragment formulas
// verbatim from the r6-r11 verified kernel). BK=64 split into 2 kh-phases of
// 16 MFMA each; per phase: {8 ds_read_b128, 3 gl2lds of K-step k+2, barrier,
// setprio(1), 16 MFMA, setprio(0), barrier}. 3 LDS buffers (stage 2 ahead);
// counted s_waitcnt vmcnt(6) ONCE per K-step (drains to 0 only at k=6) --
// loads stay in flight across barriers (T4), phase-split gives setprio (T5)
// something to arbitrate (m218: +38-73% vs drain-0). Our slab LDS layout is
// lane-linear => conflict-free, so T2 swizzle is unnecessary here.
// Epilogue: r11-verified LDS-coalesced stores, 4 passes of 64 rows.
// MODE 0: qkv epilogue -> bf16 q (x0.125) / k / v [bh][n][64]
// MODE 1: out epilogue (+bias, fp32 row-major)
// ---------------------------------------------------------------------------
template<int MODE>
__global__ __launch_bounds__(512, 2) void gemm8p(
    const u16* __restrict__ A, const u16* __restrict__ BT,
    u16* __restrict__ Cq, u16* __restrict__ Ck, u16* __restrict__ Cv,
    float* __restrict__ Cout, const float* __restrict__ bias)
{
    // 3 buffers x 48KB. Per buffer: A = 32 units (slab s=0..15, kh=0..1) of
    // 512 u16 at (s*2+kh)*512; B = 16 units at 16384 + (s*2+kh)*512.
    __shared__ alignas(16) u16 SM[3 * 24576];          // 144 KB

    const int tid  = threadIdx.x;
    const int wave = tid >> 6, lane = tid & 63;
    const int wr = wave >> 1, wc = wave & 1;           // 4M x 2N
    const int lm = lane & 15, lq = lane >> 4;

    constexpr int NX  = (MODE == 0) ? 12 : 4;          // col panels of 128
    constexpr int MG  = 50;                            // row tiles of 256
    constexpr int NWG = NX * MG;                       // 600 / 200 (both %8==0)
    constexpr int SQ  = NWG / 8, SR = NWG % 8;
    const int orig = blockIdx.y * NX + blockIdx.x;
    const int xcd = orig & 7, loc = orig >> 3;
    const int wgid = (xcd < SR ? xcd * (SQ + 1) : SR * (SQ + 1) + (xcd - SR) * SQ) + loc;
    const int row0 = (wgid / NX) * 256;
    const int col0 = (wgid % NX) * 128;

    // staging descriptors: wave stages A units wave*4..+3, B units wave*2..+1
    const u16* ApS[4]; int offA[4];
    #pragma unroll
    for (int i = 0; i < 4; ++i) {
        int u = wave * 4 + i;                          // == s*2+kh
        int s = u >> 1, kh = u & 1;
        int ar = row0 + s * 16 + lm; if (ar >= MROWS) ar = MROWS - 1;
        ApS[i] = A + (size_t)ar * 512 + kh * 32 + lq * 8;
        offA[i] = u * 512 + lane * 8;
    }
    const u16* BpS[2]; int offB[2];
    #pragma unroll
    for (int j = 0; j < 2; ++j) {
        int v = wave * 2 + j;
        int s = v >> 1, kh = v & 1;
        int br = col0 + s * 16 + lm;                   // row of BT = out column
        BpS[j] = BT + (size_t)br * 512 + kh * 32 + lq * 8;
        offB[j] = 16384 + v * 512 + lane * 8;
    }
    u16* const bufs[3] = { SM, SM + 24576, SM + 2 * 24576 };

    // stage half ph (0/1) of K-step T into buf: 2 A-units + 1 B-unit (3 loads)
    auto stageHalf = [&](int T, int ph, u16* buf) {
        const int kn = T * 64;
        gl2lds16(ApS[ph * 2 + 0] + kn, buf + offA[ph * 2 + 0]);
        gl2lds16(ApS[ph * 2 + 1] + kn, buf + offA[ph * 2 + 1]);
        gl2lds16(BpS[ph] + kn, buf + offB[ph]);
    };

    f32x4 acc[4][4];
    #pragma unroll
    for (int i = 0; i < 4; ++i)
        #pragma unroll
        for (int j = 0; j < 4; ++j) acc[i][j] = (f32x4){0.f, 0.f, 0.f, 0.f};

    // prologue: K-steps 0 and 1 in flight (12 loads); land step 0 only.
    stageHalf(0, 0, bufs[0]); stageHalf(0, 1, bufs[0]);
    stageHalf(1, 0, bufs[1]); stageHalf(1, 1, bufs[1]);
    CFENCE;
    WAITVM6;                       // step 0's 6 landed; step 1's 6 in flight
    __builtin_amdgcn_s_barrier();
    CFENCE;

    #pragma unroll
    for (int k = 0; k < 8; ++k) {
        u16* const cur = bufs[k % 3];
        u16* const nxt = bufs[(k + 2) % 3];            // buffer freed at k-1's end
        #pragma unroll
        for (int kh = 0; kh < 2; ++kh) {
            bf16x8 af[4], bfr[4];
            #pragma unroll
            for (int mi = 0; mi < 4; ++mi)
                af[mi] = *(const bf16x8*)(cur + ((wr * 4 + mi) * 2 + kh) * 512 + lane * 8);
            #pragma unroll
            for (int ni = 0; ni < 4; ++ni)
                bfr[ni] = *(const bf16x8*)(cur + 16384 + ((wc * 4 + ni) * 2 + kh) * 512 + lane * 8);
            if (k + 2 < 8) stageHalf(k + 2, kh, nxt);
            CFENCE;
            if (kh == 1) {          // once per K-step: land k+1, keep k+2 flying
                if (k < 6)      { WAITVM6; }
                else if (k == 6){ WAITVM0; }
            }
            __builtin_amdgcn_s_barrier();
            __builtin_amdgcn_s_setprio(1);
            #pragma unroll
            for (int mi = 0; mi < 4; ++mi)
                #pragma unroll
                for (int ni = 0; ni < 4; ++ni)
                    acc[mi][ni] = __builtin_amdgcn_mfma_f32_16x16x32_bf16(
                        af[mi], bfr[ni], acc[mi][ni], 0, 0, 0);
            __builtin_amdgcn_s_setprio(0);
            __builtin_amdgcn_s_barrier();
            CFENCE;
        }
    }
    __syncthreads();               // all compute done; SM free for epilogue

    // ---- epilogue via LDS: four 64-row passes, 16B coalesced stores ----
    if (MODE == 0) {
        u16* E16 = SM;                       // [64][136] u16
        const int t3 = col0 >> 9;            // 0=q 1=k 2=v (uniform per block)
        const int h0 = (col0 & 511) >> 6;    // first head of this 128-col panel
        u16* const dst = (t3 == 0) ? Cq : ((t3 == 1) ? Ck : Cv);
        const float qs = (t3 == 0) ? 0.125f : 1.0f;
        #pragma unroll
        for (int pass = 0; pass < 4; ++pass) {
            if (wr == pass) {
                #pragma unroll
                for (int mi = 0; mi < 4; ++mi)
                    #pragma unroll
                    for (int r = 0; r < 4; ++r) {
                        int row = mi * 16 + lq * 4 + r;
                        #pragma unroll
                        for (int ni = 0; ni < 4; ++ni)
                            E16[row * 136 + wc * 64 + ni * 16 + lm] =
                                f2bf(acc[mi][ni][r] * qs);
                    }
            }
            __syncthreads();
            #pragma unroll
            for (int s = 0; s < 2; ++s) {
                int hr = (tid >> 4) + s * 32;      // 0..63
                int sg = tid & 15;                 // 16B segment
                int gr = row0 + pass * 64 + hr;
                if (gr < MROWS) {
                    u16x8 v8 = *(const u16x8*)&E16[hr * 136 + sg * 8];
                    int b = gr / NTOT, n = gr - b * NTOT;
                    int h = h0 + (sg >> 3);
                    size_t tok = (size_t)(b * H_ + h) * NTOT + n;
                    *(u16x8*)&dst[tok * 64 + (sg & 7) * 8] = v8;
                }
            }
            __syncthreads();
        }
    } else {
        float* Ef = (float*)SM;              // [64][132] f32
        #pragma unroll
        for (int pass = 0; pass < 4; ++pass) {
            if (wr == pass) {
                #pragma unroll
                for (int mi = 0; mi < 4; ++mi)
                    #pragma unroll
                    for (int r = 0; r < 4; ++r) {
                        int row = mi * 16 + lq * 4 + r;
                        #pragma unroll
                        for (int ni = 0; ni < 4; ++ni)
                            Ef[row * 132 + wc * 64 + ni * 16 + lm] = acc[mi][ni][r];
                    }
            }
            __syncthreads();
            #pragma unroll
            for (int s = 0; s < 4; ++s) {
                int hr = (tid >> 5) + s * 16;      // 0..63
                int seg = tid & 31;                // float4 segment
                int gr = row0 + pass * 64 + hr;
                if (gr < MROWS) {
                    float4 v = *(const float4*)&Ef[hr * 132 + seg * 4];
                    float4 bb = *(const float4*)&bias[col0 + seg * 4];
                    v.x += bb.x; v.y += bb.y; v.z += bb.z; v.w += bb.w;
                    *(float4*)&Cout[(size_t)gr * 512 + col0 + seg * 4] = v;
                }
            }
            __syncthreads();
        }
    }
}

// ---------------------------------------------------------------------------
// group-resident local attention + fused cls partial (r10/r11-verified).
// ---------------------------------------------------------------------------
__global__ __launch_bounds__(512) void attn_group_kernel(
    const u16* __restrict__ qb, const u16* __restrict__ kb,
    const u16* __restrict__ vb, u16* __restrict__ attn,
    float* __restrict__ cls_m, float* __restrict__ cls_l,
    float* __restrict__ cls_o)
{
    __shared__ alignas(16) u16 Ksm[208 * KSTRIDE];
    __shared__ alignas(16) u16 Vsm[64 * VSTRIDE];
    __shared__ alignas(16) u16 Pbuf[8 * 16 * PSTRIDE];
    __shared__ float qs[64];
    __shared__ float ps[208];
    __shared__ float redm[8], redl[8];
    __shared__ float so[8][64];

    const int tid  = threadIdx.x;
    const int wave = tid >> 6, lane = tid & 63;
    const int lm = lane & 15, lq = lane >> 4;
    const int gf = blockIdx.x;            // bh*16 + f
    const int f  = gf & 15;
    const int bh = gf >> 4;
    const int b = bh >> 3, h = bh & 7;
    const size_t kbase = (size_t)bh * NTOT;

    if (tid < 64) qs[tid] = bf2f(qb[kbase * 64 + tid]);
    for (int idx = tid; idx < 208 * 8; idx += 512) {
        int j = idx >> 3, c = idx & 7;
        u16x8 v8 = {0, 0, 0, 0, 0, 0, 0, 0};
        if (j < 197) {
            int n = (j == 0) ? 0 : (f * NP_ + j);      // 1 + f*196 + (j-1)
            v8 = *(const u16x8*)(kb + (kbase + n) * 64 + c * 8);
        }
        *(u16x8*)(&Ksm[j * KSTRIDE + c * 8]) = v8;
    }
    for (int idx = tid; idx < 8 * 224; idx += 512) {
        int c = idx / 224, j = idx - c * 224;
        u16x8 v8 = {0, 0, 0, 0, 0, 0, 0, 0};
        if (j < 197) {
            int n = (j == 0) ? 0 : (f * NP_ + j);
            v8 = *(const u16x8*)(vb + (kbase + n) * 64 + c * 8);
        }
        #pragma unroll
        for (int e = 0; e < 8; ++e)
            Vsm[(c * 8 + e) * VSTRIDE + j] = v8[e];
    }
    __syncthreads();

    // ================= fused cls partial (all from LDS) =================
    float sj = -INFINITY;
    if (tid < 208) {
        const bool valid = (tid < 197) && (tid > 0 || f == 0);
        if (valid) {
            const u16* kr = &Ksm[tid * KSTRIDE];
            float s0 = 0.f, s1 = 0.f, s2 = 0.f, s3 = 0.f;
            #pragma unroll
            for (int i = 0; i < 8; ++i) {
                u16x8 k8 = *(const u16x8*)(kr + i * 8);
                const float* qp = qs + i * 8;
                s0 = fmaf(qp[0], bf2f(k8[0]), s0);
                s1 = fmaf(qp[1], bf2f(k8[1]), s1);
                s2 = fmaf(qp[2], bf2f(k8[2]), s2);
                s3 = fmaf(qp[3], bf2f(k8[3]), s3);
                s0 = fmaf(qp[4], bf2f(k8[4]), s0);
                s1 = fmaf(qp[5], bf2f(k8[5]), s1);
                s2 = fmaf(qp[6], bf2f(k8[6]), s2);
                s3 = fmaf(qp[7], bf2f(k8[7]), s3);
            }
            sj = (s0 + s1) + (s2 + s3);
        }
    }
    float mx = sj;
    #pragma unroll
    for (int off = 1; off < 64; off <<= 1) mx = fmaxf(mx, __shfl_xor(mx, off, 64));
    if (lane == 0) redm[wave] = mx;
    __syncthreads();
    mx = fmaxf(fmaxf(fmaxf(redm[0], redm[1]), fmaxf(redm[2], redm[3])),
               fmaxf(fmaxf(redm[4], redm[5]), fmaxf(redm[6], redm[7])));
    float pv = __expf(sj - mx);
    float lsum = pv;
    #pragma unroll
    for (int off = 1; off < 64; off <<= 1) lsum += __shfl_xor(lsum, off, 64);
    if (lane == 0) redl[wave] = lsum;
    if (tid < 208) ps[tid] = pv;
    __syncthreads();
    lsum = ((redl[0] + redl[1]) + (redl[2] + redl[3]))
         + ((redl[4] + redl[5]) + (redl[6] + redl[7]));
    {
        const int d = lane, part = wave;
        float o = 0.f;
        #pragma unroll
        for (int i = 0; i < 26; ++i) {
            int j = part * 26 + i;
            o = fmaf(ps[j], bf2f(Vsm[d * VSTRIDE + j]), o);
        }
        so[part][d] = o;
    }
    __syncthreads();
    if (tid < 64) {
        float O = ((so[0][tid] + so[1][tid]) + (so[2][tid] + so[3][tid]))
                + ((so[4][tid] + so[5][tid]) + (so[6][tid] + so[7][tid]));
        cls_o[(size_t)gf * 64 + tid] = O;
        if (tid == 0) { cls_m[gf] = mx; cls_l[gf] = lsum; }
    }
    // ====================================================================

    u16* P = Pbuf + wave * 16 * PSTRIDE;
    {
        u16x4 z4 = {0, 0, 0, 0};
        *(u16x4*)(P + lm * PSTRIDE + 208 + lq * 4) = z4;
    }

    for (int mt = wave; mt < 13; mt += 8) {
        const int rq = min(mt * 16 + lm, 195);
        const u16* qrow = qb + (kbase + (1 + f * NP_ + rq)) * 64;
        bf16x8 qf0 = *(const bf16x8*)(qrow + lq * 8);
        bf16x8 qf1 = *(const bf16x8*)(qrow + 32 + lq * 8);

        f32x4 S[13];
        #pragma unroll
        for (int nt = 0; nt < 13; ++nt) {
            const u16* krow = &Ksm[(nt * 16 + lm) * KSTRIDE];
            bf16x8 kf0 = *(const bf16x8*)(krow + lq * 8);
            bf16x8 kf1 = *(const bf16x8*)(krow + 32 + lq * 8);
            f32x4 z = (f32x4){0.f, 0.f, 0.f, 0.f};
            z = __builtin_amdgcn_mfma_f32_16x16x32_bf16(qf0, kf0, z, 0, 0, 0);
            z = __builtin_amdgcn_mfma_f32_16x16x32_bf16(qf1, kf1, z, 0, 0, 0);
            S[nt] = z;
        }

        #pragma unroll
        for (int nt = 0; nt < 13; ++nt)
            if (nt * 16 + lm >= 197) {
                S[nt][0] = -INFINITY; S[nt][1] = -INFINITY;
                S[nt][2] = -INFINITY; S[nt][3] = -INFINITY;
            }

        float invl[4];
        #pragma unroll
        for (int r = 0; r < 4; ++r) {
            float rmx = -INFINITY;
            #pragma unroll
            for (int nt = 0; nt < 13; ++nt) rmx = fmaxf(rmx, S[nt][r]);
            rmx = fmaxf(rmx, __shfl_xor(rmx, 1, 64));
            rmx = fmaxf(rmx, __shfl_xor(rmx, 2, 64));
            rmx = fmaxf(rmx, __shfl_xor(rmx, 4, 64));
            rmx = fmaxf(rmx, __shfl_xor(rmx, 8, 64));
            float sum = 0.f;
            #pragma unroll
            for (int nt = 0; nt < 13; ++nt) {
                float p = __expf(S[nt][r] - rmx);
                S[nt][r] = p;
                sum += p;
            }
            sum += __shfl_xor(sum, 1, 64);
            sum += __shfl_xor(sum, 2, 64);
            sum += __shfl_xor(sum, 4, 64);
            sum += __shfl_xor(sum, 8, 64);
            invl[r] = 1.f / sum;
        }

        #pragma unroll
        for (int nt = 0; nt < 13; ++nt) {
            int col = nt * 16 + lm;
            #pragma unroll
            for (int r = 0; r < 4; ++r)
                P[(lq * 4 + r) * PSTRIDE + col] = f2bf(S[nt][r]);
        }

        f32x4 O[4];
        #pragma unroll
        for (int nd = 0; nd < 4; ++nd) O[nd] = (f32x4){0.f, 0.f, 0.f, 0.f};
        #pragma unroll
        for (int ks = 0; ks < 7; ++ks) {
            bf16x8 pf = *(const bf16x8*)(P + lm * PSTRIDE + ks * 32 + lq * 8);
            #pragma unroll
            for (int nd = 0; nd < 4; ++nd) {
                bf16x8 vf = *(const bf16x8*)(&Vsm[(nd * 16 + lm) * VSTRIDE + ks * 32 + lq * 8]);
                O[nd] = __builtin_amdgcn_mfma_f32_16x16x32_bf16(pf, vf, O[nd], 0, 0, 0);
            }
        }

        #pragma unroll
        for (int r = 0; r < 4; ++r) {
            int rql = mt * 16 + lq * 4 + r;
            if (rql >= 196) continue;
            int n = 1 + f * NP_ + rql;
            u16* dst = attn + ((size_t)b * NTOT + n) * 512 + h * 64;
            float s = invl[r];
            #pragma unroll
            for (int nd = 0; nd < 4; ++nd)
                dst[nd * 16 + lm] = f2bf(O[nd][r] * s);
        }
    }
}

// cls stage 2: merge 16 f-partials per bh, write bf16 row n=0.
__global__ __launch_bounds__(64) void attn_cls_merge_kernel(
    const float* __restrict__ cls_m, const float* __restrict__ cls_l,
    const float* __restrict__ cls_o, u16* __restrict__ attn)
{
    const int bh = blockIdx.x, lane = threadIdx.x;
    float M = -INFINITY;
    #pragma unroll
    for (int p = 0; p < 16; ++p) M = fmaxf(M, cls_m[bh * 16 + p]);
    float L = 0.f, O = 0.f;
    #pragma unroll
    for (int p = 0; p < 16; ++p) {
        float al = __expf(cls_m[bh * 16 + p] - M);
        L += cls_l[bh * 16 + p] * al;
        O += cls_o[(size_t)(bh * 16 + p) * 64 + lane] * al;
    }
    const int b = bh >> 3, h = bh & 7;
    attn[(size_t)b * NTOT * 512 + h * 64 + lane] = f2bf(O / L);
}

// ---------------------------------------------------------------------------
extern "C" void kernel_launch(void* const* d_in, const int* in_sizes, int n_in,
                              void* d_out, int out_size, void* d_ws, size_t ws_size,
                              hipStream_t stream) {
    const float* x    = (const float*)d_in[0];
    const float* wqkv = (const float*)d_in[1];
    const float* wout = (const float*)d_in[2];
    const float* bout = (const float*)d_in[3];

    u16* p = (u16*)d_ws;
    u16* xbf   = p;                    p += (size_t)MROWS * 512;  // reused as attn
    u16* attn  = xbf;                  // safe: xbf consumed by qkv gemm before attn writes
    u16* wqkvT = p;                    p += (size_t)1536 * 512;
    u16* woutT = p;                    p += (size_t)512 * 512;
    u16* qbuf  = p;                    p += QSZ_;
    u16* kbuf  = p;                    p += QSZ_;
    u16* vbuf  = p;                    p += QSZ_;
    float* clsws = (float*)p;
    float* cls_m = clsws;                       // [512]
    float* cls_l = clsws + NGF;                 // [512]
    float* cls_o = clsws + 2 * NGF;             // [512][64]
    float* outp  = (float*)d_out;

    // fused input conversions (convert_x + both weight transposes)
    prep_kernel<<<7298, 256, 0, stream>>>(x, xbf, wqkv, wqkvT, wout, woutT);
    // qkv = x @ W_qkv (8-phase MFMA, 256x128 tile, counted vmcnt)
    gemm8p<0><<<dim3(12, 50), 512, 0, stream>>>(
        xbf, wqkvT, qbuf, kbuf, vbuf, nullptr, nullptr);
    // attention: group-resident local attn + fused cls partial
    attn_group_kernel<<<512, 512, 0, stream>>>(
        qbuf, kbuf, vbuf, attn, cls_m, cls_l, cls_o);
    attn_cls_merge_kernel<<<32, 64, 0, stream>>>(cls_m, cls_l, cls_o, attn);
    // out = attn @ W_out + b_out (8-phase MFMA)
    gemm8p<1><<<dim3(4, 50), 512, 0, stream>>>(
        attn, woutT, nullptr, nullptr, nullptr, outp, bout);
}